// Round 1
// baseline (2006.713 us; speedup 1.0000x reference)
//
#include <hip/hip_runtime.h>

#define NUM_USERS_C 500000
#define EPS_F 1e-12f

// ---------------------------------------------------------------------------
// Prep kernels
// ---------------------------------------------------------------------------

// Mark nodes that already have a self-loop edge (row==col). Benign race: all
// writers store 1.
__global__ void k_loopflags(const int* __restrict__ row, const int* __restrict__ col,
                            int* __restrict__ flags, int E) {
    int e = blockIdx.x * blockDim.x + threadIdx.x;
    if (e < E) {
        int r = row[e];
        if (r == col[e]) flags[r] = 1;
    }
}

// deg[col[e]] += w[e]  (appended self-loop weights handled in k_dinv)
__global__ void k_deg(const int* __restrict__ col, const float* __restrict__ w,
                      float* __restrict__ deg, int E) {
    int e = blockIdx.x * blockDim.x + threadIdx.x;
    if (e < E) atomicAdd(&deg[col[e]], w[e]);
}

// dinv[n] = deg_total>0 ? rsqrt(max(deg_total, eps)) : 0, deg_total includes
// the appended self-loop weight (1 if node had no self-loop, else 0).
__global__ void k_dinv(const float* __restrict__ deg, const int* __restrict__ flags,
                       float* __restrict__ dinv, int N) {
    int n = blockIdx.x * blockDim.x + threadIdx.x;
    if (n < N) {
        float lw = flags[n] ? 0.0f : 1.0f;
        float d = deg[n] + lw;
        dinv[n] = (d > 0.0f) ? rsqrtf(fmaxf(d, EPS_F)) : 0.0f;
    }
}

// norm[e] = dinv[row]*w*dinv[col] for the original E edges
__global__ void k_norm(const int* __restrict__ row, const int* __restrict__ col,
                       const float* __restrict__ w, const float* __restrict__ dinv,
                       float* __restrict__ norm, int E) {
    int e = blockIdx.x * blockDim.x + threadIdx.x;
    if (e < E) norm[e] = dinv[row[e]] * w[e] * dinv[col[e]];
}

// ---------------------------------------------------------------------------
// Node features: one wave (64 lanes) per node, lane = feature dim.
// Users: l2norm(user_emb[idx]). Items: l2norm(cat(audio, 0.5*(artist+album)) @ W + b)
// ---------------------------------------------------------------------------
__global__ __launch_bounds__(256) void k_features(
    const int* __restrict__ batch_nodes,
    const float* __restrict__ user_emb, const float* __restrict__ artist_emb,
    const float* __restrict__ album_emb, const float* __restrict__ audio_emb,
    const int* __restrict__ artist_ids, const int* __restrict__ album_ids,
    const float* __restrict__ proj_w, const float* __restrict__ proj_b,
    float* __restrict__ x, float* __restrict__ acc, int N)
{
    __shared__ float Ws[128 * 64];
    for (int i = threadIdx.x; i < 128 * 64; i += blockDim.x)
        Ws[i] = proj_w[i];
    __syncthreads();

    const int lane = threadIdx.x & 63;
    const int wid = threadIdx.x >> 6;
    const int wavesPerBlock = blockDim.x >> 6;
    const int waveStride = gridDim.x * wavesPerBlock;
    const float bias = proj_b[lane];

    for (int n = blockIdx.x * wavesPerBlock + wid; n < N; n += waveStride) {
        int idx = batch_nodes[n];
        float val;
        if (idx < NUM_USERS_C) {
            val = user_emb[(size_t)idx * 64 + lane];
        } else {
            int it = idx - NUM_USERS_C;
            int aid = artist_ids[it];
            int bid = album_ids[it];
            float vlo = audio_emb[(size_t)it * 64 + lane];                      // cat[lane]
            float vhi = 0.5f * (artist_emb[(size_t)aid * 64 + lane] +
                                album_emb[(size_t)bid * 64 + lane]);            // cat[64+lane]
            float s = bias;
            #pragma unroll
            for (int k = 0; k < 64; k++)
                s = fmaf(__shfl(vlo, k, 64), Ws[k * 64 + lane], s);
            #pragma unroll
            for (int k = 0; k < 64; k++)
                s = fmaf(__shfl(vhi, k, 64), Ws[(k + 64) * 64 + lane], s);
            val = s;
        }
        // l2 normalize across the wave
        float ss = val * val;
        #pragma unroll
        for (int off = 32; off > 0; off >>= 1) ss += __shfl_xor(ss, off, 64);
        float scale = 1.0f / fmaxf(sqrtf(ss), EPS_F);
        val *= scale;
        x[(size_t)n * 64 + lane] = val;
        acc[(size_t)n * 64 + lane] = val;  // acc starts at layer-0 embedding
    }
}

// ---------------------------------------------------------------------------
// Per-layer: init destination with the self-loop contribution
// xdst[n,:] = dinv[n]^2 * loop_w[n] * xsrc[n,:]
// ---------------------------------------------------------------------------
__global__ void k_selfinit(const float* __restrict__ xsrc, float* __restrict__ xdst,
                           const float* __restrict__ dinv, const int* __restrict__ flags,
                           int M /* = N*64 */) {
    int gid = blockIdx.x * blockDim.x + threadIdx.x;
    if (gid < M) {
        int n = gid >> 6;
        float di = dinv[n];
        float lw = flags[n] ? 0.0f : 1.0f;
        xdst[gid] = di * di * lw * xsrc[gid];
    }
}

// ---------------------------------------------------------------------------
// Per-layer edge scatter: one wave per edge, lane = dim.
// xdst[col,:] += norm[e] * xsrc[row,:]
// ---------------------------------------------------------------------------
__global__ __launch_bounds__(256) void k_edges(
    const int* __restrict__ row, const int* __restrict__ col,
    const float* __restrict__ norm,
    const float* __restrict__ xsrc, float* __restrict__ xdst, int E)
{
    long long tid = (long long)blockIdx.x * blockDim.x + threadIdx.x;
    int e = (int)(tid >> 6);
    int lane = threadIdx.x & 63;
    if (e < E) {
        float nm = norm[e];
        int r = row[e];
        int c = col[e];
        float v = nm * xsrc[(size_t)r * 64 + lane];
        atomicAdd(&xdst[(size_t)c * 64 + lane], v);
    }
}

// acc += xnew
__global__ void k_accadd(float* __restrict__ acc, const float* __restrict__ xnew, int M) {
    int i = blockIdx.x * blockDim.x + threadIdx.x;
    if (i < M) acc[i] += xnew[i];
}

// out = l2norm(acc / 4) — in place on d_out; 64 consecutive threads = one node
__global__ __launch_bounds__(256) void k_final(float* __restrict__ acc, int M) {
    int gid = blockIdx.x * blockDim.x + threadIdx.x;
    if (gid < M) {
        float v = acc[gid] * 0.25f;
        float ss = v * v;
        #pragma unroll
        for (int off = 32; off > 0; off >>= 1) ss += __shfl_xor(ss, off, 64);
        float scale = 1.0f / fmaxf(sqrtf(ss), EPS_F);
        acc[gid] = v * scale;
    }
}

// ---------------------------------------------------------------------------
extern "C" void kernel_launch(void* const* d_in, const int* in_sizes, int n_in,
                              void* d_out, int out_size, void* d_ws, size_t ws_size,
                              hipStream_t stream) {
    const int*   batch_nodes = (const int*)d_in[0];
    const int*   edge_index  = (const int*)d_in[1];
    const float* edge_w      = (const float*)d_in[2];
    const float* user_emb    = (const float*)d_in[3];
    const float* artist_emb  = (const float*)d_in[4];
    const float* album_emb   = (const float*)d_in[5];
    const float* audio_emb   = (const float*)d_in[6];
    const int*   artist_ids  = (const int*)d_in[7];
    const int*   album_ids   = (const int*)d_in[8];
    const float* proj_w      = (const float*)d_in[9];
    const float* proj_b      = (const float*)d_in[10];

    const int N = in_sizes[0];
    const int E = in_sizes[2];
    const int* row = edge_index;
    const int* col = edge_index + E;
    float* out = (float*)d_out;

    // workspace carve-up (~74 MB)
    char* ws = (char*)d_ws;
    float* deg  = (float*)ws; ws += (size_t)N * sizeof(float);
    float* dinv = (float*)ws; ws += (size_t)N * sizeof(float);
    int*   flags= (int*)ws;   ws += (size_t)N * sizeof(int);
    float* norm = (float*)ws; ws += (size_t)E * sizeof(float);
    float* xA   = (float*)ws; ws += (size_t)N * 64 * sizeof(float);
    float* xB   = (float*)ws; ws += (size_t)N * 64 * sizeof(float);

    hipMemsetAsync(deg, 0, (size_t)N * sizeof(float), stream);
    hipMemsetAsync(flags, 0, (size_t)N * sizeof(int), stream);

    const int TB = 256;
    const int M = N * 64;

    k_loopflags<<<(E + TB - 1) / TB, TB, 0, stream>>>(row, col, flags, E);
    k_deg<<<(E + TB - 1) / TB, TB, 0, stream>>>(col, edge_w, deg, E);
    k_dinv<<<(N + TB - 1) / TB, TB, 0, stream>>>(deg, flags, dinv, N);
    k_norm<<<(E + TB - 1) / TB, TB, 0, stream>>>(row, col, edge_w, dinv, norm, E);

    k_features<<<4096, 256, 0, stream>>>(batch_nodes, user_emb, artist_emb, album_emb,
                                         audio_emb, artist_ids, album_ids, proj_w, proj_b,
                                         xA, out, N);

    float* xs = xA;
    float* xd = xB;
    for (int layer = 0; layer < 3; layer++) {
        k_selfinit<<<(M + TB - 1) / TB, TB, 0, stream>>>(xs, xd, dinv, flags, M);
        long long tot = (long long)E * 64;
        int eblocks = (int)((tot + TB - 1) / TB);
        k_edges<<<eblocks, TB, 0, stream>>>(row, col, norm, xs, xd, E);
        k_accadd<<<(M + TB - 1) / TB, TB, 0, stream>>>(out, xd, M);
        float* t = xs; xs = xd; xd = t;
    }

    k_final<<<(M + TB - 1) / TB, TB, 0, stream>>>(out, M);
}

// Round 2
// 1326.834 us; speedup vs baseline: 1.5124x; 1.5124x over previous
//
#include <hip/hip_runtime.h>

#define NUM_USERS_C 500000
#define EPS_F 1e-12f

// ---------------------------------------------------------------------------
// Prep kernels (run once per call; cheap vs. propagation)
// ---------------------------------------------------------------------------

// Mark nodes that already have a self-loop edge (row==col). Benign race.
__global__ void k_loopflags(const int* __restrict__ row, const int* __restrict__ col,
                            int* __restrict__ flags, int E) {
    int e = blockIdx.x * blockDim.x + threadIdx.x;
    if (e < E) {
        int r = row[e];
        if (r == col[e]) flags[r] = 1;
    }
}

// deg[col] += w  (float, for gcn_norm)  and  cnt[col] += 1 (int, for CSR)
__global__ void k_degcnt(const int* __restrict__ col, const float* __restrict__ w,
                         float* __restrict__ deg, int* __restrict__ cnt, int E) {
    int e = blockIdx.x * blockDim.x + threadIdx.x;
    if (e < E) {
        int c = col[e];
        atomicAdd(&deg[c], w[e]);
        atomicAdd(&cnt[c], 1);
    }
}

// dinv[n] = rsqrt(max(deg_total, eps)) (0 if deg_total==0), deg_total includes
// the appended self-loop weight. selfw[n] = dinv^2 * loop_w  (self-loop msg coeff).
__global__ void k_dinv(const float* __restrict__ deg, const int* __restrict__ flags,
                       float* __restrict__ dinv, float* __restrict__ selfw, int N) {
    int n = blockIdx.x * blockDim.x + threadIdx.x;
    if (n < N) {
        float lw = flags[n] ? 0.0f : 1.0f;
        float d = deg[n] + lw;
        float di = (d > 0.0f) ? rsqrtf(fmaxf(d, EPS_F)) : 0.0f;
        dinv[n] = di;
        selfw[n] = di * di * lw;
    }
}

// Exclusive scan of cnt[0..N) -> rowptr[0..N]; single 1024-thread block.
// N = 131072 -> 128 elements/thread, two passes over global (trivial volume).
__global__ __launch_bounds__(1024) void k_scan(const int* __restrict__ cnt,
                                               int* __restrict__ rowptr, int N) {
    __shared__ int ssum[1024];
    int t = threadIdx.x;
    int per = (N + 1023) >> 10;
    int base = t * per;
    int s = 0;
    for (int i = 0; i < per; i++) {
        int idx = base + i;
        if (idx < N) s += cnt[idx];
    }
    ssum[t] = s;
    __syncthreads();
    for (int d = 1; d < 1024; d <<= 1) {
        int v = (t >= d) ? ssum[t - d] : 0;
        __syncthreads();
        ssum[t] += v;
        __syncthreads();
    }
    int off = ssum[t] - s;  // exclusive prefix
    for (int i = 0; i < per; i++) {
        int idx = base + i;
        if (idx < N) { rowptr[idx] = off; off += cnt[idx]; }
    }
    if (t == 1023) rowptr[N] = off;
}

// Scatter edges into CSR order keyed by destination (col): emeta[pos] = {row, norm}
__global__ void k_scatter(const int* __restrict__ row, const int* __restrict__ col,
                          const float* __restrict__ w, const float* __restrict__ dinv,
                          const int* __restrict__ rowptr, int* __restrict__ cursor,
                          int2* __restrict__ emeta, int E) {
    int e = blockIdx.x * blockDim.x + threadIdx.x;
    if (e < E) {
        int r = row[e], c = col[e];
        float nm = dinv[r] * w[e] * dinv[c];
        int pos = rowptr[c] + atomicAdd(&cursor[c], 1);
        emeta[pos] = make_int2(r, __float_as_int(nm));
    }
}

// ---------------------------------------------------------------------------
// Node features: one wave (64 lanes) per node, lane = feature dim.
// ---------------------------------------------------------------------------
__global__ __launch_bounds__(256) void k_features(
    const int* __restrict__ batch_nodes,
    const float* __restrict__ user_emb, const float* __restrict__ artist_emb,
    const float* __restrict__ album_emb, const float* __restrict__ audio_emb,
    const int* __restrict__ artist_ids, const int* __restrict__ album_ids,
    const float* __restrict__ proj_w, const float* __restrict__ proj_b,
    float* __restrict__ x, float* __restrict__ acc, int N)
{
    __shared__ float Ws[128 * 64];
    for (int i = threadIdx.x; i < 128 * 64; i += blockDim.x)
        Ws[i] = proj_w[i];
    __syncthreads();

    const int lane = threadIdx.x & 63;
    const int wid = threadIdx.x >> 6;
    const int wavesPerBlock = blockDim.x >> 6;
    const int waveStride = gridDim.x * wavesPerBlock;
    const float bias = proj_b[lane];

    for (int n = blockIdx.x * wavesPerBlock + wid; n < N; n += waveStride) {
        int idx = batch_nodes[n];
        float val;
        if (idx < NUM_USERS_C) {
            val = user_emb[(size_t)idx * 64 + lane];
        } else {
            int it = idx - NUM_USERS_C;
            int aid = artist_ids[it];
            int bid = album_ids[it];
            float vlo = audio_emb[(size_t)it * 64 + lane];
            float vhi = 0.5f * (artist_emb[(size_t)aid * 64 + lane] +
                                album_emb[(size_t)bid * 64 + lane]);
            float s = bias;
            #pragma unroll
            for (int k = 0; k < 64; k++)
                s = fmaf(__shfl(vlo, k, 64), Ws[k * 64 + lane], s);
            #pragma unroll
            for (int k = 0; k < 64; k++)
                s = fmaf(__shfl(vhi, k, 64), Ws[(k + 64) * 64 + lane], s);
            val = s;
        }
        float ss = val * val;
        #pragma unroll
        for (int off = 32; off > 0; off >>= 1) ss += __shfl_xor(ss, off, 64);
        float scale = 1.0f / fmaxf(sqrtf(ss), EPS_F);
        val *= scale;
        x[(size_t)n * 64 + lane] = val;
        acc[(size_t)n * 64 + lane] = val;
    }
}

// ---------------------------------------------------------------------------
// CSR propagation: one wave per destination node, lane = dim.
// a = selfw[n]*xs[n] + sum_e norm_e * xs[row_e];  xd[n]=a;  acc[n]+=a
// ---------------------------------------------------------------------------
__global__ __launch_bounds__(256) void k_prop(
    const int* __restrict__ rowptr, const int2* __restrict__ emeta,
    const float* __restrict__ selfw,
    const float* __restrict__ xs, float* __restrict__ xd,
    float* __restrict__ acc, int N)
{
    int lane = threadIdx.x & 63;
    int node = blockIdx.x * 4 + (threadIdx.x >> 6);
    if (node >= N) return;
    int beg = rowptr[node], end = rowptr[node + 1];
    float a = selfw[node] * xs[(size_t)node * 64 + lane];
    int p = beg;
    for (; p + 1 < end; p += 2) {
        int2 m0 = emeta[p];
        int2 m1 = emeta[p + 1];
        float v0 = xs[(size_t)m0.x * 64 + lane];
        float v1 = xs[(size_t)m1.x * 64 + lane];
        a = fmaf(__int_as_float(m0.y), v0, a);
        a = fmaf(__int_as_float(m1.y), v1, a);
    }
    if (p < end) {
        int2 m = emeta[p];
        a = fmaf(__int_as_float(m.y), xs[(size_t)m.x * 64 + lane], a);
    }
    xd[(size_t)node * 64 + lane] = a;
    acc[(size_t)node * 64 + lane] += a;
}

// Last layer: same gather, then fold acc-add, /4, and l2norm; write out only.
__global__ __launch_bounds__(256) void k_prop_final(
    const int* __restrict__ rowptr, const int2* __restrict__ emeta,
    const float* __restrict__ selfw,
    const float* __restrict__ xs, float* __restrict__ acc_out, int N)
{
    int lane = threadIdx.x & 63;
    int node = blockIdx.x * 4 + (threadIdx.x >> 6);
    if (node >= N) return;
    int beg = rowptr[node], end = rowptr[node + 1];
    float a = selfw[node] * xs[(size_t)node * 64 + lane];
    int p = beg;
    for (; p + 1 < end; p += 2) {
        int2 m0 = emeta[p];
        int2 m1 = emeta[p + 1];
        float v0 = xs[(size_t)m0.x * 64 + lane];
        float v1 = xs[(size_t)m1.x * 64 + lane];
        a = fmaf(__int_as_float(m0.y), v0, a);
        a = fmaf(__int_as_float(m1.y), v1, a);
    }
    if (p < end) {
        int2 m = emeta[p];
        a = fmaf(__int_as_float(m.y), xs[(size_t)m.x * 64 + lane], a);
    }
    float v = (acc_out[(size_t)node * 64 + lane] + a) * 0.25f;
    float ss = v * v;
    #pragma unroll
    for (int off = 32; off > 0; off >>= 1) ss += __shfl_xor(ss, off, 64);
    float scale = 1.0f / fmaxf(sqrtf(ss), EPS_F);
    acc_out[(size_t)node * 64 + lane] = v * scale;
}

// ---------------------------------------------------------------------------
extern "C" void kernel_launch(void* const* d_in, const int* in_sizes, int n_in,
                              void* d_out, int out_size, void* d_ws, size_t ws_size,
                              hipStream_t stream) {
    const int*   batch_nodes = (const int*)d_in[0];
    const int*   edge_index  = (const int*)d_in[1];
    const float* edge_w      = (const float*)d_in[2];
    const float* user_emb    = (const float*)d_in[3];
    const float* artist_emb  = (const float*)d_in[4];
    const float* album_emb   = (const float*)d_in[5];
    const float* audio_emb   = (const float*)d_in[6];
    const int*   artist_ids  = (const int*)d_in[7];
    const int*   album_ids   = (const int*)d_in[8];
    const float* proj_w      = (const float*)d_in[9];
    const float* proj_b      = (const float*)d_in[10];

    const int N = in_sizes[0];
    const int E = in_sizes[2];
    const int* row = edge_index;
    const int* col = edge_index + E;
    float* out = (float*)d_out;   // doubles as acc

    // workspace carve-up
    char* ws = (char*)d_ws;
    float* deg    = (float*)ws; ws += (size_t)N * sizeof(float);
    float* dinv   = (float*)ws; ws += (size_t)N * sizeof(float);
    float* selfw  = (float*)ws; ws += (size_t)N * sizeof(float);
    int*   flags  = (int*)ws;   ws += (size_t)N * sizeof(int);
    int*   cnt    = (int*)ws;   ws += (size_t)N * sizeof(int);
    int*   cursor = (int*)ws;   ws += (size_t)N * sizeof(int);
    int*   rowptr = (int*)ws;   ws += (size_t)(N + 1) * sizeof(int);
    ws = (char*)(((uintptr_t)ws + 15) & ~(uintptr_t)15);
    int2*  emeta  = (int2*)ws;  ws += (size_t)E * sizeof(int2);
    float* xA     = (float*)ws; ws += (size_t)N * 64 * sizeof(float);
    float* xB     = (float*)ws; ws += (size_t)N * 64 * sizeof(float);

    hipMemsetAsync(deg, 0, (size_t)N * sizeof(float), stream);
    hipMemsetAsync(flags, 0, (size_t)N * sizeof(int), stream);
    hipMemsetAsync(cnt, 0, (size_t)N * sizeof(int), stream);
    hipMemsetAsync(cursor, 0, (size_t)N * sizeof(int), stream);

    const int TB = 256;
    const int M = N * 64;
    (void)M;

    k_loopflags<<<(E + TB - 1) / TB, TB, 0, stream>>>(row, col, flags, E);
    k_degcnt<<<(E + TB - 1) / TB, TB, 0, stream>>>(col, edge_w, deg, cnt, E);
    k_dinv<<<(N + TB - 1) / TB, TB, 0, stream>>>(deg, flags, dinv, selfw, N);
    k_scan<<<1, 1024, 0, stream>>>(cnt, rowptr, N);
    k_scatter<<<(E + TB - 1) / TB, TB, 0, stream>>>(row, col, edge_w, dinv,
                                                    rowptr, cursor, emeta, E);

    k_features<<<4096, 256, 0, stream>>>(batch_nodes, user_emb, artist_emb, album_emb,
                                         audio_emb, artist_ids, album_ids, proj_w, proj_b,
                                         xA, out, N);

    int pblocks = (N + 3) / 4;  // 4 waves (nodes) per 256-thread block
    k_prop<<<pblocks, 256, 0, stream>>>(rowptr, emeta, selfw, xA, xB, out, N);
    k_prop<<<pblocks, 256, 0, stream>>>(rowptr, emeta, selfw, xB, xA, out, N);
    k_prop_final<<<pblocks, 256, 0, stream>>>(rowptr, emeta, selfw, xA, out, N);
}

// Round 3
// 1034.933 us; speedup vs baseline: 1.9390x; 1.2820x over previous
//
#include <hip/hip_runtime.h>

#define NUM_USERS_C 500000
#define EPS_F 1e-12f

// ---------------------------------------------------------------------------
// Prep: one pass over edges — self-loop flags, weighted degree, edge counts
// ---------------------------------------------------------------------------
__global__ void k_edgeprep(const int* __restrict__ row, const int* __restrict__ col,
                           const float* __restrict__ w,
                           int* __restrict__ flags, float* __restrict__ deg,
                           int* __restrict__ cnt, int E) {
    int e = blockIdx.x * blockDim.x + threadIdx.x;
    if (e < E) {
        int r = row[e], c = col[e];
        if (r == c) flags[r] = 1;          // benign race, all store 1
        atomicAdd(&deg[c], w[e]);
        atomicAdd(&cnt[c], 1);
    }
}

// dinv = rsqrt(max(deg_total,eps)) (0 if 0); selfw = dinv^2 * loop_w
__global__ void k_dinv(const float* __restrict__ deg, const int* __restrict__ flags,
                       float* __restrict__ dinv, float* __restrict__ selfw, int N) {
    int n = blockIdx.x * blockDim.x + threadIdx.x;
    if (n < N) {
        float lw = flags[n] ? 0.0f : 1.0f;
        float d = deg[n] + lw;
        float di = (d > 0.0f) ? rsqrtf(fmaxf(d, EPS_F)) : 0.0f;
        dinv[n] = di;
        selfw[n] = di * di * lw;
    }
}

// ---------------------------------------------------------------------------
// Two-level exclusive scan: cnt[0..N) -> rowptr[0..N]
// ---------------------------------------------------------------------------
__global__ __launch_bounds__(256) void k_blocksum(const int* __restrict__ cnt,
                                                  int* __restrict__ bsum, int N) {
    __shared__ int s[256];
    int i = blockIdx.x * 256 + threadIdx.x;
    s[threadIdx.x] = (i < N) ? cnt[i] : 0;
    __syncthreads();
    for (int d = 128; d > 0; d >>= 1) {
        if (threadIdx.x < d) s[threadIdx.x] += s[threadIdx.x + d];
        __syncthreads();
    }
    if (threadIdx.x == 0) bsum[blockIdx.x] = s[0];
}

// Single block: exclusive scan of NB (<=1024) block sums; also writes rowptr[N].
__global__ __launch_bounds__(1024) void k_scanbsum(const int* __restrict__ bsum,
                                                   int* __restrict__ boff,
                                                   int* __restrict__ rowptr,
                                                   int NB, int N) {
    __shared__ int s[1024];
    int t = threadIdx.x;
    int v = (t < NB) ? bsum[t] : 0;
    s[t] = v;
    __syncthreads();
    for (int d = 1; d < 1024; d <<= 1) {
        int u = (t >= d) ? s[t - d] : 0;
        __syncthreads();
        s[t] += u;
        __syncthreads();
    }
    if (t < NB) boff[t] = s[t] - v;       // exclusive prefix of block sums
    if (t == 1023) rowptr[N] = s[1023];   // grand total
}

__global__ __launch_bounds__(256) void k_rowptr(const int* __restrict__ cnt,
                                                const int* __restrict__ boff,
                                                int* __restrict__ rowptr, int N) {
    __shared__ int s[256];
    int i = blockIdx.x * 256 + threadIdx.x;
    int v = (i < N) ? cnt[i] : 0;
    s[threadIdx.x] = v;
    __syncthreads();
    for (int d = 1; d < 256; d <<= 1) {
        int u = (threadIdx.x >= d) ? s[threadIdx.x - d] : 0;
        __syncthreads();
        s[threadIdx.x] += u;
        __syncthreads();
    }
    if (i < N) rowptr[i] = boff[blockIdx.x] + s[threadIdx.x] - v;  // exclusive
}

// Scatter edges into CSR order keyed by destination: emeta[pos] = {row, norm}
__global__ void k_scatter(const int* __restrict__ row, const int* __restrict__ col,
                          const float* __restrict__ w, const float* __restrict__ dinv,
                          const int* __restrict__ rowptr, int* __restrict__ cursor,
                          int2* __restrict__ emeta, int E) {
    int e = blockIdx.x * blockDim.x + threadIdx.x;
    if (e < E) {
        int r = row[e], c = col[e];
        float nm = dinv[r] * w[e] * dinv[c];
        int pos = rowptr[c] + atomicAdd(&cursor[c], 1);
        emeta[pos] = make_int2(r, __float_as_int(nm));
    }
}

// ---------------------------------------------------------------------------
// Node features: one wave per node, lane = dim.
// ---------------------------------------------------------------------------
__global__ __launch_bounds__(256) void k_features(
    const int* __restrict__ batch_nodes,
    const float* __restrict__ user_emb, const float* __restrict__ artist_emb,
    const float* __restrict__ album_emb, const float* __restrict__ audio_emb,
    const int* __restrict__ artist_ids, const int* __restrict__ album_ids,
    const float* __restrict__ proj_w, const float* __restrict__ proj_b,
    float* __restrict__ x, float* __restrict__ acc, int N)
{
    __shared__ float Ws[128 * 64];
    for (int i = threadIdx.x; i < 128 * 64; i += blockDim.x)
        Ws[i] = proj_w[i];
    __syncthreads();

    const int lane = threadIdx.x & 63;
    const int wid = threadIdx.x >> 6;
    const int wavesPerBlock = blockDim.x >> 6;
    const int waveStride = gridDim.x * wavesPerBlock;
    const float bias = proj_b[lane];

    for (int n = blockIdx.x * wavesPerBlock + wid; n < N; n += waveStride) {
        int idx = batch_nodes[n];
        float val;
        if (idx < NUM_USERS_C) {
            val = user_emb[(size_t)idx * 64 + lane];
        } else {
            int it = idx - NUM_USERS_C;
            int aid = artist_ids[it];
            int bid = album_ids[it];
            float vlo = audio_emb[(size_t)it * 64 + lane];
            float vhi = 0.5f * (artist_emb[(size_t)aid * 64 + lane] +
                                album_emb[(size_t)bid * 64 + lane]);
            float s = bias;
            #pragma unroll
            for (int k = 0; k < 64; k++)
                s = fmaf(__shfl(vlo, k, 64), Ws[k * 64 + lane], s);
            #pragma unroll
            for (int k = 0; k < 64; k++)
                s = fmaf(__shfl(vhi, k, 64), Ws[(k + 64) * 64 + lane], s);
            val = s;
        }
        float ss = val * val;
        #pragma unroll
        for (int off = 32; off > 0; off >>= 1) ss += __shfl_xor(ss, off, 64);
        float scale = 1.0f / fmaxf(sqrtf(ss), EPS_F);
        val *= scale;
        x[(size_t)n * 64 + lane] = val;
        acc[(size_t)n * 64 + lane] = val;
    }
}

// ---------------------------------------------------------------------------
// CSR propagation: one wave per dest node, lane = dim. Lanes cooperatively
// load up to 64 edge records in ONE coalesced load, then broadcast via shfl
// and issue 8 independent row-gathers at a time.
// ---------------------------------------------------------------------------
__device__ __forceinline__ float prop_accum(
    const int* __restrict__ rowptr, const int2* __restrict__ emeta,
    const float* __restrict__ selfw, const float* __restrict__ xs,
    int node, int lane)
{
    int beg = rowptr[node], end = rowptr[node + 1];
    float a = selfw[node] * xs[(size_t)node * 64 + lane];
    for (int base = beg; base < end; base += 64) {
        int chunk = min(64, end - base);
        int2 m = make_int2(0, 0);
        if (lane < chunk) m = emeta[base + lane];   // coalesced 8B/lane
        int j = 0;
        for (; j + 8 <= chunk; j += 8) {
            int r0 = __shfl(m.x, j + 0); float w0 = __int_as_float(__shfl(m.y, j + 0));
            int r1 = __shfl(m.x, j + 1); float w1 = __int_as_float(__shfl(m.y, j + 1));
            int r2 = __shfl(m.x, j + 2); float w2 = __int_as_float(__shfl(m.y, j + 2));
            int r3 = __shfl(m.x, j + 3); float w3 = __int_as_float(__shfl(m.y, j + 3));
            int r4 = __shfl(m.x, j + 4); float w4 = __int_as_float(__shfl(m.y, j + 4));
            int r5 = __shfl(m.x, j + 5); float w5 = __int_as_float(__shfl(m.y, j + 5));
            int r6 = __shfl(m.x, j + 6); float w6 = __int_as_float(__shfl(m.y, j + 6));
            int r7 = __shfl(m.x, j + 7); float w7 = __int_as_float(__shfl(m.y, j + 7));
            float v0 = xs[(size_t)r0 * 64 + lane];
            float v1 = xs[(size_t)r1 * 64 + lane];
            float v2 = xs[(size_t)r2 * 64 + lane];
            float v3 = xs[(size_t)r3 * 64 + lane];
            float v4 = xs[(size_t)r4 * 64 + lane];
            float v5 = xs[(size_t)r5 * 64 + lane];
            float v6 = xs[(size_t)r6 * 64 + lane];
            float v7 = xs[(size_t)r7 * 64 + lane];
            a = fmaf(w0, v0, a); a = fmaf(w1, v1, a);
            a = fmaf(w2, v2, a); a = fmaf(w3, v3, a);
            a = fmaf(w4, v4, a); a = fmaf(w5, v5, a);
            a = fmaf(w6, v6, a); a = fmaf(w7, v7, a);
        }
        for (; j < chunk; j++) {
            int r = __shfl(m.x, j); float wv = __int_as_float(__shfl(m.y, j));
            a = fmaf(wv, xs[(size_t)r * 64 + lane], a);
        }
    }
    return a;
}

__global__ __launch_bounds__(256) void k_prop(
    const int* __restrict__ rowptr, const int2* __restrict__ emeta,
    const float* __restrict__ selfw,
    const float* __restrict__ xs, float* __restrict__ xd,
    float* __restrict__ acc, int N)
{
    int lane = threadIdx.x & 63;
    int node = blockIdx.x * 4 + (threadIdx.x >> 6);
    if (node >= N) return;
    float a = prop_accum(rowptr, emeta, selfw, xs, node, lane);
    xd[(size_t)node * 64 + lane] = a;
    acc[(size_t)node * 64 + lane] += a;
}

// Last layer: fold acc-add, /4, l2norm; write out only.
__global__ __launch_bounds__(256) void k_prop_final(
    const int* __restrict__ rowptr, const int2* __restrict__ emeta,
    const float* __restrict__ selfw,
    const float* __restrict__ xs, float* __restrict__ acc_out, int N)
{
    int lane = threadIdx.x & 63;
    int node = blockIdx.x * 4 + (threadIdx.x >> 6);
    if (node >= N) return;
    float a = prop_accum(rowptr, emeta, selfw, xs, node, lane);
    float v = (acc_out[(size_t)node * 64 + lane] + a) * 0.25f;
    float ss = v * v;
    #pragma unroll
    for (int off = 32; off > 0; off >>= 1) ss += __shfl_xor(ss, off, 64);
    float scale = 1.0f / fmaxf(sqrtf(ss), EPS_F);
    acc_out[(size_t)node * 64 + lane] = v * scale;
}

// ---------------------------------------------------------------------------
extern "C" void kernel_launch(void* const* d_in, const int* in_sizes, int n_in,
                              void* d_out, int out_size, void* d_ws, size_t ws_size,
                              hipStream_t stream) {
    const int*   batch_nodes = (const int*)d_in[0];
    const int*   edge_index  = (const int*)d_in[1];
    const float* edge_w      = (const float*)d_in[2];
    const float* user_emb    = (const float*)d_in[3];
    const float* artist_emb  = (const float*)d_in[4];
    const float* album_emb   = (const float*)d_in[5];
    const float* audio_emb   = (const float*)d_in[6];
    const int*   artist_ids  = (const int*)d_in[7];
    const int*   album_ids   = (const int*)d_in[8];
    const float* proj_w      = (const float*)d_in[9];
    const float* proj_b      = (const float*)d_in[10];

    const int N = in_sizes[0];
    const int E = in_sizes[2];
    const int* row = edge_index;
    const int* col = edge_index + E;
    float* out = (float*)d_out;   // doubles as acc

    const int NB = (N + 255) / 256;   // blocks for the two-level scan (512)

    // workspace carve-up
    char* ws = (char*)d_ws;
    float* deg    = (float*)ws; ws += (size_t)N * sizeof(float);
    float* dinv   = (float*)ws; ws += (size_t)N * sizeof(float);
    float* selfw  = (float*)ws; ws += (size_t)N * sizeof(float);
    int*   flags  = (int*)ws;   ws += (size_t)N * sizeof(int);
    int*   cnt    = (int*)ws;   ws += (size_t)N * sizeof(int);
    int*   cursor = (int*)ws;   ws += (size_t)N * sizeof(int);
    int*   rowptr = (int*)ws;   ws += (size_t)(N + 1) * sizeof(int);
    int*   bsum   = (int*)ws;   ws += (size_t)NB * sizeof(int);
    int*   boff   = (int*)ws;   ws += (size_t)NB * sizeof(int);
    ws = (char*)(((uintptr_t)ws + 15) & ~(uintptr_t)15);
    int2*  emeta  = (int2*)ws;  ws += (size_t)E * sizeof(int2);
    float* xA     = (float*)ws; ws += (size_t)N * 64 * sizeof(float);
    float* xB     = (float*)ws; ws += (size_t)N * 64 * sizeof(float);

    hipMemsetAsync(deg, 0, (size_t)N * sizeof(float), stream);
    hipMemsetAsync(flags, 0, (size_t)N * sizeof(int), stream);
    hipMemsetAsync(cnt, 0, (size_t)N * sizeof(int), stream);
    hipMemsetAsync(cursor, 0, (size_t)N * sizeof(int), stream);

    const int TB = 256;

    k_edgeprep<<<(E + TB - 1) / TB, TB, 0, stream>>>(row, col, edge_w, flags, deg, cnt, E);
    k_dinv<<<(N + TB - 1) / TB, TB, 0, stream>>>(deg, flags, dinv, selfw, N);
    k_blocksum<<<NB, 256, 0, stream>>>(cnt, bsum, N);
    k_scanbsum<<<1, 1024, 0, stream>>>(bsum, boff, rowptr, NB, N);
    k_rowptr<<<NB, 256, 0, stream>>>(cnt, boff, rowptr, N);
    k_scatter<<<(E + TB - 1) / TB, TB, 0, stream>>>(row, col, edge_w, dinv,
                                                    rowptr, cursor, emeta, E);

    k_features<<<4096, 256, 0, stream>>>(batch_nodes, user_emb, artist_emb, album_emb,
                                         audio_emb, artist_ids, album_ids, proj_w, proj_b,
                                         xA, out, N);

    int pblocks = (N + 3) / 4;  // 4 waves (nodes) per 256-thread block
    k_prop<<<pblocks, 256, 0, stream>>>(rowptr, emeta, selfw, xA, xB, out, N);
    k_prop<<<pblocks, 256, 0, stream>>>(rowptr, emeta, selfw, xB, xA, out, N);
    k_prop_final<<<pblocks, 256, 0, stream>>>(rowptr, emeta, selfw, xA, out, N);
}